// Round 6
// baseline (302.070 us; speedup 1.0000x reference)
//
#include <hip/hip_runtime.h>
#include <hip/hip_cooperative_groups.h>
#include <math.h>

namespace cg = cooperative_groups;

#define C    5
#define NPC  400
#define DF   64
#define HH   256
#define DOUT 64
#define EPC  12800
#define NN   (C*NPC)    // 2000
#define NE   (C*EPC)    // 64000
#define NBLK 260
#define NTHR 256
#define NTOT (NBLK*NTHR)

// workspace offsets (floats)
#define OFF_AMAT 0
#define OFF_DEG  800000
#define OFF_TA   802000
#define OFF_TB   804000
#define OFF_XW   806000     // 512000
#define OFF_WA2  1318000    // 1280
#define OFF_WB2  1319280    // 1280
#define OFF_CAB  1320560    // 10 (+2 pad)
#define OFF_AV   1320572    // 2000
#define OFF_BV   1322572    // 2000
#define OFF_ST   1324572    // 2

// ---- tiled f32 GEMM tile body: BM=32 BN=64 BK=16, 256 thr, 2x4/thread ----
// FUSETAB=0: plain store to outc. FUSETAB=1: relu(acc+bias)·{wa2,wb2} row-reduced into ta/tb.
template<int K, int FUSETAB>
__device__ void gemm_tile(const float* __restrict__ Ab, const float* __restrict__ Bb,
                          const float* __restrict__ biasc, float* __restrict__ outc,
                          const float* __restrict__ wa2c, const float* __restrict__ wb2c,
                          float* __restrict__ tac, float* __restrict__ tbc,
                          int m0, int n0, int tid,
                          float As[16][34], float Bs[16][68]) {
    const int tx = tid & 15, ty = tid >> 4;
    const int lrowA = tid >> 3, lk2 = (tid & 7) << 1;    // A loader: 32 rows x 16 k (float2)
    const int lkb = tid >> 4, lcol4 = (tid & 15) << 2;   // B loader: 16 k x 64 cols (float4)
    float acc[2][4] = {};
    for (int k0 = 0; k0 < K; k0 += 16) {
        float2 a2 = make_float2(0.f, 0.f);
        int gr = m0 + lrowA;
        if (gr < NPC) a2 = *(const float2*)(Ab + (size_t)gr*K + k0 + lk2);
        As[lk2][lrowA] = a2.x; As[lk2+1][lrowA] = a2.y;
        *(float4*)&Bs[lkb][lcol4] = *(const float4*)(Bb + (size_t)(k0+lkb)*HH + n0 + lcol4);
        __syncthreads();
        #pragma unroll
        for (int kk = 0; kk < 16; ++kk) {
            float2 a = *(float2*)&As[kk][ty << 1];
            float4 b = *(float4*)&Bs[kk][tx << 2];
            acc[0][0] += a.x*b.x; acc[0][1] += a.x*b.y; acc[0][2] += a.x*b.z; acc[0][3] += a.x*b.w;
            acc[1][0] += a.y*b.x; acc[1][1] += a.y*b.y; acc[1][2] += a.y*b.z; acc[1][3] += a.y*b.w;
        }
        __syncthreads();
    }
    if (FUSETAB) {
        float pa0 = 0.f, pa1 = 0.f, pb0 = 0.f, pb1 = 0.f;
        #pragma unroll
        for (int j = 0; j < 4; ++j) {
            int col = n0 + (tx << 2) + j;
            float bj  = biasc[col];
            float waj = wa2c[col];
            float wbj = wb2c[col];
            float o0 = fmaxf(acc[0][j] + bj, 0.f);
            float o1 = fmaxf(acc[1][j] + bj, 0.f);
            pa0 += o0*waj; pa1 += o1*waj;
            pb0 += o0*wbj; pb1 += o1*wbj;
        }
        #pragma unroll
        for (int off = 1; off < 16; off <<= 1) {
            pa0 += __shfl_xor(pa0, off); pa1 += __shfl_xor(pa1, off);
            pb0 += __shfl_xor(pb0, off); pb1 += __shfl_xor(pb1, off);
        }
        if (tx == 0) {
            int gr0 = m0 + (ty << 1);
            if (gr0 < NPC)     { atomicAdd(&tac[gr0],     pa0); atomicAdd(&tbc[gr0],     pb0); }
            if (gr0 + 1 < NPC) { atomicAdd(&tac[gr0 + 1], pa1); atomicAdd(&tbc[gr0 + 1], pb1); }
        }
    } else {
        #pragma unroll
        for (int i = 0; i < 2; ++i) {
            int gr = m0 + (ty << 1) + i;
            if (gr < NPC)
                *(float4*)(outc + (size_t)gr*HH + n0 + (tx << 2)) =
                    make_float4(acc[i][0], acc[i][1], acc[i][2], acc[i][3]);
        }
    }
}

__global__ __launch_bounds__(NTHR, 2) void mega_kernel(
        const float* __restrict__ x, const float* __restrict__ ew,
        const float* __restrict__ W1, const float* __restrict__ b1,
        const float* __restrict__ W2, const float* __restrict__ b2,
        const float* __restrict__ Watt, const float* __restrict__ batt,
        const int* __restrict__ ei, float* __restrict__ out, float* __restrict__ ws) {
    cg::grid_group grid = cg::this_grid();
    __shared__ float As[16][34];
    __shared__ float Bs[16][68];
    __shared__ double wred[5][4];
    __shared__ double wsum[4];

    float* Amat = ws + OFF_AMAT;
    float* deg  = ws + OFF_DEG;
    float* ta   = ws + OFF_TA;
    float* tb   = ws + OFF_TB;
    float* xW   = ws + OFF_XW;
    float* wa2  = ws + OFF_WA2;
    float* wb2  = ws + OFF_WB2;
    float* cab  = ws + OFF_CAB;
    float* av   = ws + OFF_AV;
    float* bv   = ws + OFF_BV;
    float* st   = ws + OFF_ST;

    const int bid = blockIdx.x, tid = threadIdx.x;
    const int gtid = bid*NTHR + tid;
    const int wid = tid >> 6, lane = tid & 63;

    // ---- P0: zero Amat + deg + ta + tb (806000 floats = 201500 float4) ----
    {
        float4* z = (float4*)ws;
        for (int i = gtid; i < 201500; i += NTOT)
            z[i] = make_float4(0.f, 0.f, 0.f, 0.f);
    }
    grid.sync();

    // ---- P1: deg scatter  ||  wprep  ||  gemm1 (xW = x@W1) ----
    for (int idx = gtid; idx < NE; idx += NTOT) {
        int c = idx / EPC, e = idx % EPC;
        int col = ei[(size_t)c*2*EPC + EPC + e];
        atomicAdd(&deg[c*NPC + col], ew[(size_t)c*EPC + e]);
    }
    for (int W = bid*4 + wid; W < C*HH + 2*C; W += NBLK*4) {
        if (W < C*HH) {
            int c = W / HH, k = W % HH;
            float v  = W2[((size_t)c*HH + k)*DOUT + lane];
            float sa = v*Watt[lane];
            float sb = v*Watt[DOUT + lane];
            for (int off = 32; off; off >>= 1) { sa += __shfl_down(sa, off); sb += __shfl_down(sb, off); }
            if (!lane) { wa2[W] = sa; wb2[W] = sb; }
        } else {
            int j = W - C*HH, which = j / C, c = j % C;
            float s = b2[c*DOUT + lane]*Watt[which*DOUT + lane];
            for (int off = 32; off; off >>= 1) s += __shfl_down(s, off);
            if (!lane) cab[which*C + c] = s;
        }
    }
    {
        int c = bid/52, rem = bid%52, mj = rem%13, nj = rem/13;
        gemm_tile<DF, 0>(x + (size_t)c*NPC*DF, W1 + (size_t)c*DF*HH, nullptr,
                         xW + (size_t)c*NPC*HH, nullptr, nullptr, nullptr, nullptr,
                         mj*32, nj*64, tid, As, Bs);
    }
    grid.sync();

    // ---- P2: adjacency scatter: A[c][col][row] += dis_r*w*dis_c; diag += 1/(deg+1) ----
    for (int idx = gtid; idx < NE; idx += NTOT) {
        int c = idx / EPC, e = idx % EPC;
        const int* rowp = ei + (size_t)c*2*EPC;
        int r  = rowp[e];
        int cc = rowp[EPC + e];
        float w  = ew[(size_t)c*EPC + e];
        float dr = rsqrtf(deg[c*NPC + r]  + 1.0f);
        float dc = rsqrtf(deg[c*NPC + cc] + 1.0f);
        atomicAdd(&Amat[(size_t)c*NPC*NPC + (size_t)cc*NPC + r], dr*w*dc);
    }
    if (gtid < NN) {
        int c = gtid / NPC, n = gtid % NPC;
        atomicAdd(&Amat[(size_t)c*NPC*NPC + (size_t)n*NPC + n], 1.0f/(deg[gtid] + 1.0f));
    }
    grid.sync();

    // ---- P3: gemm2 (relu(A@xW+b1)) with fused ta/tb epilogue ----
    {
        int c = bid/52, rem = bid%52, mj = rem%13, nj = rem/13;
        gemm_tile<NPC, 1>(Amat + (size_t)c*NPC*NPC, xW + (size_t)c*NPC*HH,
                          b1 + c*HH, nullptr, wa2 + c*HH, wb2 + c*HH,
                          ta + c*NPC, tb + c*NPC, mj*32, nj*64, tid, As, Bs);
    }
    grid.sync();

    // ---- P4: avbv: av[n] = A_row(n)·ta + b2·Wa (one wave per node) ----
    for (int w = bid*4 + wid; w < NN; w += NBLK*4) {
        int c = w / NPC, n = w % NPC;
        const float* Ar  = Amat + (size_t)c*NPC*NPC + (size_t)n*NPC;
        const float* tac = ta + c*NPC;
        const float* tbc = tb + c*NPC;
        float sa = 0.f, sb = 0.f;
        for (int m = lane; m < NPC; m += 64) { float a = Ar[m]; sa += a*tac[m]; sb += a*tbc[m]; }
        for (int off = 32; off; off >>= 1) { sa += __shfl_down(sa, off); sb += __shfl_down(sb, off); }
        if (!lane) { av[w] = sa + cab[c]; bv[w] = sb + cab[C + c]; }
    }
    grid.sync();

    // ---- P5: stats in block 0 (closed-form mean/std over all P pairs, f64) ----
    if (bid == 0) {
        const int CH = 8;
        int lo = tid*CH, hi = lo + CH; if (hi > NN) hi = NN; if (lo > NN) lo = NN;
        double sa1=0, sb1=0, sa2=0, sb2=0, csum=0;
        for (int i = lo; i < hi; ++i) {
            double a = av[i], b = bv[i];
            double wa = (double)(NN-1-i), wb = (double)i;
            sa1 += a*wa; sb1 += b*wb;
            sa2 += a*a*wa; sb2 += b*b*wb;
            csum += a;
        }
        double v0=sa1, v1=sb1, v2=sa2, v3=sb2;
        for (int off = 32; off; off >>= 1) {
            v0 += __shfl_down(v0, off); v1 += __shfl_down(v1, off);
            v2 += __shfl_down(v2, off); v3 += __shfl_down(v3, off);
        }
        if (!lane) { wred[0][wid]=v0; wred[1][wid]=v1; wred[2][wid]=v2; wred[3][wid]=v3; }
        double xx = csum;
        for (int off = 1; off < 64; off <<= 1) {
            double y = __shfl_up(xx, off);
            if (lane >= off) xx += y;
        }
        if (lane == 63) wsum[wid] = xx;
        __syncthreads();
        double woff = 0;
        for (int wI = 0; wI < wid; ++wI) woff += wsum[wI];
        double run = woff + xx - csum;
        double ct = 0;
        for (int i = lo; i < hi; ++i) { ct += (double)bv[i]*run; run += (double)av[i]; }
        for (int off = 32; off; off >>= 1) ct += __shfl_down(ct, off);
        if (!lane) wred[4][wid] = ct;
        __syncthreads();
        if (tid == 0) {
            double T0=0, T1=0, T2=0, T3=0, CT=0;
            for (int wI = 0; wI < 4; ++wI) {
                T0 += wred[0][wI]; T1 += wred[1][wI]; T2 += wred[2][wI];
                T3 += wred[3][wI]; CT += wred[4][wI];
            }
            double cc2 = (double)batt[0];
            double P  = (double)NN*(double)(NN-1)/2.0;
            double S1 = T0 + T1 + cc2*P;
            double S2 = T2 + T3 + 2.0*CT + 2.0*cc2*S1 - cc2*cc2*P;
            double m  = S1/P;
            double var = (S2 - S1*S1/P)/(P - 1.0);
            st[0] = (float)m;
            st[1] = (float)sqrt(var);
        }
    }
    grid.sync();

    // ---- P6: all-pairs sigmoid output ----
    {
        float m = st[0], s = st[1];
        float inv = 1.0f/s;
        float bb = batt[0];
        for (int i = bid; i < NN; i += NBLK) {
            long off = (long)i*(NN-1) - ((long)i*(i-1))/2;
            float ai = av[i] + bb - m;
            for (int j = i + 1 + tid; j < NN; j += NTHR) {
                float z = (ai + bv[j]) * inv;
                out[off + (j - i - 1)] = 1.0f/(1.0f + __expf(-z));
            }
        }
    }
}

extern "C" void kernel_launch(void* const* d_in, const int* in_sizes, int n_in,
                              void* d_out, int out_size, void* d_ws, size_t ws_size,
                              hipStream_t stream) {
    const float* x    = (const float*)d_in[0];
    const float* ew   = (const float*)d_in[1];
    const float* W1   = (const float*)d_in[2];
    const float* b1   = (const float*)d_in[3];
    const float* W2   = (const float*)d_in[4];
    const float* b2   = (const float*)d_in[5];
    const float* Watt = (const float*)d_in[6];
    const float* batt = (const float*)d_in[7];
    const int*   ei   = (const int*)d_in[8];
    float* out = (float*)d_out;
    float* ws  = (float*)d_ws;

    void* args[] = {(void*)&x, (void*)&ew, (void*)&W1, (void*)&b1, (void*)&W2,
                    (void*)&b2, (void*)&Watt, (void*)&batt, (void*)&ei,
                    (void*)&out, (void*)&ws};
    hipLaunchCooperativeKernel((void*)mega_kernel, dim3(NBLK), dim3(NTHR),
                               args, 0, stream);
}

// Round 9
// 145.467 us; speedup vs baseline: 2.0765x; 2.0765x over previous
//
#include <hip/hip_runtime.h>
#include <math.h>

#define C    5
#define NPC  400
#define DF   64
#define HH   256
#define DOUT 64
#define EPC  12800
#define NN   (C*NPC)    // 2000
#define NE   (C*EPC)    // 64000

// ---------------- K1: zero workspace (Amat/deg/ta/tb) + wprep ----------------
// wprep: wa2[c,k] = W2[c,k,:]·Wa, wb2 = ·Wb; cab[which*C+c] = b2[c]·W{a,b}
__global__ void init_wprep_kernel(const float* __restrict__ W2, const float* __restrict__ Watt,
                                  const float* __restrict__ b2, float* __restrict__ ws,
                                  float* __restrict__ wa2, float* __restrict__ wb2,
                                  float* __restrict__ cab) {
    const int bid = blockIdx.x, tid = threadIdx.x;
    const int gtid = bid*256 + tid;
    // zero Amat+deg+ta+tb = 806000 floats = 201500 float4 (contiguous at ws)
    float4* z = (float4*)ws;
    for (int i = gtid; i < 201500; i += 325*256)
        z[i] = make_float4(0.f, 0.f, 0.f, 0.f);
    // wave jobs: 1280 wa2/wb2 rows + 10 cab dots (1290 <= 325*4 waves)
    int W = bid*4 + (tid >> 6);
    int lane = tid & 63;
    if (W < C*HH) {
        int c = W / HH, k = W % HH;
        float v  = W2[((size_t)c*HH + k)*DOUT + lane];
        float sa = v*Watt[lane];
        float sb = v*Watt[DOUT + lane];
        for (int off = 32; off; off >>= 1) { sa += __shfl_down(sa, off); sb += __shfl_down(sb, off); }
        if (!lane) { wa2[W] = sa; wb2[W] = sb; }
    } else if (W < C*HH + 2*C) {
        int j = W - C*HH, which = j / C, c = j % C;
        float s = b2[c*DOUT + lane]*Watt[which*DOUT + lane];
        for (int off = 32; off; off >>= 1) s += __shfl_down(s, off);
        if (!lane) cab[which*C + c] = s;
    }
}

// ---------------- K2: deg scatter || gemm1 (xW = x@W1), BM=32 BN=64 BK=16 ----------------
__global__ __launch_bounds__(256) void deg_gemm1_kernel(
        const float* __restrict__ ew, const int* __restrict__ ei, float* __restrict__ deg,
        const float* __restrict__ x, const float* __restrict__ W1, float* __restrict__ xW) {
    const int bid = blockIdx.x, tid = threadIdx.x;
    const int gtid = bid*256 + tid;
    // deg scatter: one atomic per thread (66560 >= 64000)
    if (gtid < NE) {
        int c = gtid / EPC, e = gtid % EPC;
        int col = ei[(size_t)c*2*EPC + EPC + e];
        atomicAdd(&deg[c*NPC + col], ew[(size_t)c*EPC + e]);
    }
    // gemm1 tile: 52 tiles/cluster (13 m x 4 n) x 5 clusters = 260 blocks
    __shared__ float As[16][34];
    __shared__ float Bs[16][68];
    const int c = bid/52, rem = bid%52;
    const int m0 = (rem%13) << 5, n0 = (rem/13) << 6;
    const float* Ab = x + (size_t)c*NPC*DF;
    const float* Bb = W1 + (size_t)c*DF*HH;
    const int tx = tid & 15, ty = tid >> 4;
    const int lrowA = tid >> 3, lk2 = (tid & 7) << 1;
    const int lkb = tid >> 4, lcol4 = (tid & 15) << 2;
    float acc[2][4] = {};
    for (int k0 = 0; k0 < DF; k0 += 16) {
        float2 a2 = make_float2(0.f, 0.f);
        int gr = m0 + lrowA;
        if (gr < NPC) a2 = *(const float2*)(Ab + (size_t)gr*DF + k0 + lk2);
        As[lk2][lrowA] = a2.x; As[lk2+1][lrowA] = a2.y;
        *(float4*)&Bs[lkb][lcol4] = *(const float4*)(Bb + (size_t)(k0+lkb)*HH + n0 + lcol4);
        __syncthreads();
        #pragma unroll
        for (int kk = 0; kk < 16; ++kk) {
            float2 a = *(float2*)&As[kk][ty << 1];
            float4 b = *(float4*)&Bs[kk][tx << 2];
            acc[0][0] += a.x*b.x; acc[0][1] += a.x*b.y; acc[0][2] += a.x*b.z; acc[0][3] += a.x*b.w;
            acc[1][0] += a.y*b.x; acc[1][1] += a.y*b.y; acc[1][2] += a.y*b.z; acc[1][3] += a.y*b.w;
        }
        __syncthreads();
    }
    #pragma unroll
    for (int i = 0; i < 2; ++i) {
        int gr = m0 + (ty << 1) + i;
        if (gr < NPC)
            *(float4*)(xW + (size_t)c*NPC*HH + (size_t)gr*HH + n0 + (tx << 2)) =
                make_float4(acc[i][0], acc[i][1], acc[i][2], acc[i][3]);
    }
}

// ---------------- K3: adjacency scatter ----------------
// A[c][col][row] += dis_r*w*dis_c, dis = rsqrt(deg+1); diag += 1/(deg+1)
__global__ void adj_kernel(const float* __restrict__ ew, const int* __restrict__ ei,
                           const float* __restrict__ deg, float* __restrict__ Amat) {
    int idx = blockIdx.x*256 + threadIdx.x;
    if (idx < NE) {
        int c = idx / EPC, e = idx % EPC;
        const int* rowp = ei + (size_t)c*2*EPC;
        int r  = rowp[e];
        int cc = rowp[EPC + e];
        float w  = ew[(size_t)c*EPC + e];
        float dr = rsqrtf(deg[c*NPC + r]  + 1.0f);
        float dc = rsqrtf(deg[c*NPC + cc] + 1.0f);
        atomicAdd(&Amat[(size_t)c*NPC*NPC + (size_t)cc*NPC + r], dr*w*dc);
    }
    if (idx < NN) {
        int c = idx / NPC, n = idx % NPC;
        atomicAdd(&Amat[(size_t)c*NPC*NPC + (size_t)n*NPC + n], 1.0f/(deg[idx] + 1.0f));
    }
}

// ---------------- K4: gemm2 + fused ta/tb epilogue, BM=16 BN=64 BK=16, 500 blocks ----------
// ta[row] += sum_col relu(A@xW + b1)[row][col] * wa2[col]  (same for tb/wb2)
__global__ __launch_bounds__(256) void gemm2_tab_kernel(
        const float* __restrict__ Amat, const float* __restrict__ xW,
        const float* __restrict__ b1, const float* __restrict__ wa2,
        const float* __restrict__ wb2, float* __restrict__ ta, float* __restrict__ tb) {
    __shared__ float As[16][17];
    __shared__ float Bs[16][68];
    const int bid = blockIdx.x, tid = threadIdx.x;
    const int c = bid/100, rem = bid%100;
    const int m0 = (rem%25) << 4, n0 = (rem/25) << 6;
    const float* Ab = Amat + (size_t)c*NPC*NPC;
    const float* Bb = xW + (size_t)c*NPC*HH;
    const int tx = tid & 15, ty = tid >> 4;
    const int lkb = tid >> 4, lcol4 = (tid & 15) << 2;
    float acc[4] = {};
    for (int k0 = 0; k0 < NPC; k0 += 16) {
        // A loader: 16 rows x 16 k, one float/thread (row = ty, k = tx)
        As[tx][ty] = Ab[(size_t)(m0 + ty)*NPC + k0 + tx];
        *(float4*)&Bs[lkb][lcol4] = *(const float4*)(Bb + (size_t)(k0+lkb)*HH + n0 + lcol4);
        __syncthreads();
        #pragma unroll
        for (int kk = 0; kk < 16; ++kk) {
            float a  = As[kk][ty];
            float4 b = *(float4*)&Bs[kk][tx << 2];
            acc[0] += a*b.x; acc[1] += a*b.y; acc[2] += a*b.z; acc[3] += a*b.w;
        }
        __syncthreads();
    }
    float pa = 0.f, pb = 0.f;
    #pragma unroll
    for (int j = 0; j < 4; ++j) {
        int col = n0 + (tx << 2) + j;
        float o = fmaxf(acc[j] + b1[c*HH + col], 0.f);
        pa += o*wa2[c*HH + col];
        pb += o*wb2[c*HH + col];
    }
    #pragma unroll
    for (int off = 1; off < 16; off <<= 1) {
        pa += __shfl_xor(pa, off);
        pb += __shfl_xor(pb, off);
    }
    if (tx == 0) {
        atomicAdd(&ta[c*NPC + m0 + ty], pa);
        atomicAdd(&tb[c*NPC + m0 + ty], pb);
    }
}

// ---------------- K5: avbv: av[n] = A_row(n)·ta + b2·Wa (one wave per node) ----------------
__global__ void avbv_kernel(const float* __restrict__ Amat, const float* __restrict__ ta,
                            const float* __restrict__ tb, const float* __restrict__ cab,
                            float* __restrict__ av, float* __restrict__ bv) {
    int w = blockIdx.x*4 + (threadIdx.x >> 6);
    int lane = threadIdx.x & 63;
    if (w >= NN) return;
    int c = w / NPC, n = w % NPC;
    const float* Ar  = Amat + (size_t)c*NPC*NPC + (size_t)n*NPC;
    const float* tac = ta + c*NPC;
    const float* tbc = tb + c*NPC;
    float sa = 0.f, sb = 0.f;
    for (int m = lane; m < NPC; m += 64) { float a = Ar[m]; sa += a*tac[m]; sb += a*tbc[m]; }
    for (int off = 32; off; off >>= 1) { sa += __shfl_down(sa, off); sb += __shfl_down(sb, off); }
    if (!lane) { av[w] = sa + cab[c]; bv[w] = sb + cab[C + c]; }
}

// ---------------- K6: redundant per-block stats (f64) + all-pairs sigmoid row ----------------
__global__ void pair_stats_kernel(const float* __restrict__ av, const float* __restrict__ bv,
                                  const float* __restrict__ batt, float* __restrict__ out) {
    __shared__ double wred[5][4];
    __shared__ double wsum[4];
    __shared__ float sms[2];
    const int tid = threadIdx.x;
    const int lane = tid & 63, wid = tid >> 6;
    // ---- stats (identical deterministic computation in every block) ----
    const int CH = 8;
    int lo = tid*CH, hi = lo + CH; if (hi > NN) hi = NN; if (lo > NN) lo = NN;
    double sa1=0, sb1=0, sa2=0, sb2=0, csum=0;
    for (int i = lo; i < hi; ++i) {
        double a = av[i], b = bv[i];
        double wa = (double)(NN-1-i), wb = (double)i;
        sa1 += a*wa; sb1 += b*wb;
        sa2 += a*a*wa; sb2 += b*b*wb;
        csum += a;
    }
    double v0=sa1, v1=sb1, v2=sa2, v3=sb2;
    for (int off = 32; off; off >>= 1) {
        v0 += __shfl_down(v0, off); v1 += __shfl_down(v1, off);
        v2 += __shfl_down(v2, off); v3 += __shfl_down(v3, off);
    }
    if (!lane) { wred[0][wid]=v0; wred[1][wid]=v1; wred[2][wid]=v2; wred[3][wid]=v3; }
    double xx = csum;
    for (int off = 1; off < 64; off <<= 1) {
        double y = __shfl_up(xx, off);
        if (lane >= off) xx += y;
    }
    if (lane == 63) wsum[wid] = xx;
    __syncthreads();
    double woff = 0;
    for (int wI = 0; wI < wid; ++wI) woff += wsum[wI];
    double run = woff + xx - csum;
    double ct = 0;
    for (int i = lo; i < hi; ++i) { ct += (double)bv[i]*run; run += (double)av[i]; }
    for (int off = 32; off; off >>= 1) ct += __shfl_down(ct, off);
    if (!lane) wred[4][wid] = ct;
    __syncthreads();
    if (tid == 0) {
        double T0=0, T1=0, T2=0, T3=0, CT=0;
        for (int wI = 0; wI < 4; ++wI) {
            T0 += wred[0][wI]; T1 += wred[1][wI]; T2 += wred[2][wI];
            T3 += wred[3][wI]; CT += wred[4][wI];
        }
        double cc2 = (double)batt[0];
        double P  = (double)NN*(double)(NN-1)/2.0;
        double S1 = T0 + T1 + cc2*P;
        double S2 = T2 + T3 + 2.0*CT + 2.0*cc2*S1 - cc2*cc2*P;
        sms[0] = (float)(S1/P);
        sms[1] = (float)sqrt((S2 - S1*S1/P)/(P - 1.0));
    }
    __syncthreads();
    // ---- pair row i = blockIdx.x ----
    const int i = blockIdx.x;
    long off = (long)i*(NN-1) - ((long)i*(i-1))/2;
    float m = sms[0], inv = 1.0f/sms[1];
    float ai = av[i] + batt[0] - m;
    for (int j = i + 1 + tid; j < NN; j += 256) {
        float z = (ai + bv[j]) * inv;
        out[off + (j - i - 1)] = 1.0f/(1.0f + __expf(-z));
    }
}

extern "C" void kernel_launch(void* const* d_in, const int* in_sizes, int n_in,
                              void* d_out, int out_size, void* d_ws, size_t ws_size,
                              hipStream_t stream) {
    const float* x    = (const float*)d_in[0];
    const float* ew   = (const float*)d_in[1];
    const float* W1   = (const float*)d_in[2];
    const float* b1   = (const float*)d_in[3];
    const float* W2   = (const float*)d_in[4];
    const float* b2   = (const float*)d_in[5];
    const float* Watt = (const float*)d_in[6];
    const float* batt = (const float*)d_in[7];
    const int*   ei   = (const int*)d_in[8];
    float* out = (float*)d_out;
    float* ws  = (float*)d_ws;

    // workspace layout (floats) — first 806000 zeroed by K1
    float* Amat = ws;                  // 800000
    float* deg  = Amat + 800000;       // 2000
    float* ta   = deg  + 2000;         // 2000
    float* tb   = ta   + 2000;         // 2000
    float* xW   = tb   + 2000;         // 512000
    float* wa2  = xW   + 512000;       // 1280
    float* wb2  = wa2  + 1280;         // 1280
    float* cab  = wb2  + 1280;         // 10 (+2 pad)
    float* av   = cab  + 12;           // 2000
    float* bv   = av   + 2000;         // 2000

    init_wprep_kernel<<<325, 256, 0, stream>>>(W2, Watt, b2, ws, wa2, wb2, cab);
    deg_gemm1_kernel<<<260, 256, 0, stream>>>(ew, ei, deg, x, W1, xW);
    adj_kernel<<<250, 256, 0, stream>>>(ew, ei, deg, Amat);
    gemm2_tab_kernel<<<500, 256, 0, stream>>>(Amat, xW, b1, wa2, wb2, ta, tb);
    avbv_kernel<<<500, 256, 0, stream>>>(Amat, ta, tb, cab, av, bv);
    pair_stats_kernel<<<NN, 256, 0, stream>>>(av, bv, batt, out);
}